// Round 4
// baseline (4899.128 us; speedup 1.0000x reference)
//
#include <hip/hip_runtime.h>
#include <hip/hip_bf16.h>
#include <cstdint>
#include <cstddef>

// B=64 T=512 E=768 H=256 L=9.  BiLSTM + linear + CRF loglik (scalar out).
// R4: recurrence with weights pinned in VGPRs via ATOMIC loads (defeats
// rematerialization that sank them back to L2 in R3 — VGPR_Count was 96).
// MFMA operand order swapped: C=[gate-unit][batch] so each lane owns one
// batch x 4 consecutive hu -> single 8B h store, 4x8B xg loads, and NO
// __syncthreads in the loop (per-wave flag protocol, target 64 waves).

typedef __attribute__((ext_vector_type(8))) short short8;
typedef __attribute__((ext_vector_type(4))) float floatx4;
typedef unsigned short ushort_t;
typedef unsigned int uint_t;
typedef unsigned long long ull_t;

#define NB   64
#define NT   512
#define NE   768
#define NH   256
#define NL   9
#define NG   1024   // 4*H
#define NCC  2048   // both dirs' gates
#define GPD  8      // workgroups per direction
#define NWAVES 64   // flag target: GPD * 8 waves
#define HSLOT 16384 // 64*256 elems per h time-slot

__device__ inline float b2f(ushort_t u) {
    union { uint_t i; float f; } v; v.i = ((uint_t)u) << 16; return v.f;
}
__device__ inline ushort_t f2b(float f) {
    union { float f; uint_t i; } v; v.f = f;
    uint_t r = (v.i + 0x7FFFu + ((v.i >> 16) & 1u)) >> 16;
    return (ushort_t)r;
}
__device__ inline float sigf(float x) { return 1.0f / (1.0f + __expf(-x)); }
__device__ inline float tanhfast(float x) { return 1.0f - 2.0f / (1.0f + __expf(2.0f * x)); }

// ---------------- K0: zero sync counters + h time-slot 0 --------------------
__global__ void zero_k(int* __restrict__ cnt, ushort_t* __restrict__ hglob) {
    int tid = blockIdx.x * blockDim.x + threadIdx.x;   // 1024 threads
    cnt[tid] = 0;                                      // 2*512 ints
    uint_t* h0 = (uint_t*)hglob;                       // dir0 slot0 (8192 uints)
    uint_t* h1 = (uint_t*)(hglob + (size_t)513 * HSLOT);
    for (int i = tid; i < HSLOT / 2; i += 1024) { h0[i] = 0; h1[i] = 0; }
}

// ---------------- K1: embeddings (B,T,E) f32 -> xbf (T,B,E) bf16 ------------
__global__ void conv_x(const float* __restrict__ emb, ushort_t* __restrict__ xbf) {
    int id = blockIdx.x * blockDim.x + threadIdx.x;      // over T*B*(E/4)
    int t  = id / (NB * (NE / 4));
    int rm = id - t * (NB * (NE / 4));
    int b  = rm / (NE / 4);
    int e4 = rm - b * (NE / 4);
    const float4 v = *(const float4*)(emb + ((size_t)b * NT + t) * NE + e4 * 4);
    ushort_t o[4] = { f2b(v.x), f2b(v.y), f2b(v.z), f2b(v.w) };
    *(uint2*)(xbf + ((size_t)t * NB + b) * NE + e4 * 4) = *(const uint2*)o;
}

// ---------------- K1b: weights -> bf16 (Wcat, Whh), bias concat -------------
__global__ void conv_w(const float* __restrict__ Wihf, const float* __restrict__ Wihb,
                       const float* __restrict__ Whhf, const float* __restrict__ Whhb,
                       const float* __restrict__ bf,   const float* __restrict__ bb,
                       ushort_t* __restrict__ wcat, ushort_t* __restrict__ whh,
                       float* __restrict__ bias) {
    int idx = blockIdx.x * blockDim.x + threadIdx.x;
    const int NW1 = NCC * NE;            // 1572864
    const int NW2 = 2 * NG * NH;         // 524288
    if (idx < NW1) {
        int row = idx / NE, col = idx - row * NE;
        float s = (row < NG) ? Wihf[(size_t)row * NE + col]
                             : Wihb[(size_t)(row - NG) * NE + col];
        wcat[idx] = f2b(s);
    } else if (idx < NW1 + NW2) {
        int j = idx - NW1;
        float s = (j < NG * NH) ? Whhf[j] : Whhb[j - NG * NH];
        whh[j] = f2b(s);
    } else if (idx < NW1 + NW2 + NCC) {
        int j = idx - NW1 - NW2;
        bias[j] = (j < NG) ? bf[j] : bb[j - NG];
    }
}

// ---------------- K2: xg = xbf(32768x768) @ wcat^T(2048x768) + bias ---------
__global__ __launch_bounds__(256) void gemm_xg(const ushort_t* __restrict__ A,
                                               const ushort_t* __restrict__ W,
                                               const float* __restrict__ bias,
                                               ushort_t* __restrict__ C) {
    __shared__ ushort_t As[128 * 72];
    __shared__ ushort_t Bs[128 * 72];
    const int tid = threadIdx.x;
    const int wave = tid >> 6, lane = tid & 63;
    const int q = lane >> 4, m16 = lane & 15;
    const int wm = wave & 1, wn = wave >> 1;
    const int m0 = blockIdx.y * 128, n0 = blockIdx.x * 128;

    floatx4 acc[4][4];
    #pragma unroll
    for (int i = 0; i < 4; ++i)
        #pragma unroll
        for (int j = 0; j < 4; ++j) acc[i][j] = (floatx4){0.f, 0.f, 0.f, 0.f};

    for (int kt = 0; kt < NE / 64; ++kt) {
        __syncthreads();
        #pragma unroll
        for (int it = 0; it < 4; ++it) {
            int chunk = tid + it * 256;         // 0..1023
            int row = chunk >> 3, kc = chunk & 7;
            *(uint4*)(&As[row * 72 + kc * 8]) =
                *(const uint4*)(A + (size_t)(m0 + row) * NE + kt * 64 + kc * 8);
            *(uint4*)(&Bs[row * 72 + kc * 8]) =
                *(const uint4*)(W + (size_t)(n0 + row) * NE + kt * 64 + kc * 8);
        }
        __syncthreads();
        #pragma unroll
        for (int ks = 0; ks < 2; ++ks) {
            short8 af[4], bfr[4];
            #pragma unroll
            for (int mt = 0; mt < 4; ++mt)
                af[mt] = *(const short8*)(&As[(wm * 64 + mt * 16 + m16) * 72 + ks * 32 + q * 8]);
            #pragma unroll
            for (int nt = 0; nt < 4; ++nt)
                bfr[nt] = *(const short8*)(&Bs[(wn * 64 + nt * 16 + m16) * 72 + ks * 32 + q * 8]);
            #pragma unroll
            for (int mt = 0; mt < 4; ++mt)
                #pragma unroll
                for (int nt = 0; nt < 4; ++nt)
                    acc[mt][nt] = __builtin_amdgcn_mfma_f32_16x16x32_bf16(
                        af[mt], bfr[nt], acc[mt][nt], 0, 0, 0);
        }
    }
    float bcol[4];
    #pragma unroll
    for (int nt = 0; nt < 4; ++nt) bcol[nt] = bias[n0 + wn * 64 + nt * 16 + m16];
    #pragma unroll
    for (int mt = 0; mt < 4; ++mt)
        #pragma unroll
        for (int nt = 0; nt < 4; ++nt) {
            int gn = n0 + wn * 64 + nt * 16 + m16;
            #pragma unroll
            for (int r = 0; r < 4; ++r) {
                int gm = m0 + wm * 64 + mt * 16 + q * 4 + r;
                C[(size_t)gm * NCC + gn] = f2b(acc[mt][nt][r] + bcol[nt]);
            }
        }
}

// ---------------- K3: recurrence, 16 WGs = 2 dirs x 8 hu-slices -------------
// WG (d,g) owns hidden units [g*32, g*32+32).  512 threads = 8 waves =
// (hg: hu subgroup of 16) x (bq: batch quarter of 16).  Weights in VGPRs
// (atomic-loaded once -> non-rematerializable).  Per lane: batch = bq*16+m16,
// hu = g*32+hg*16+q*4+r (C rows = gate units, C cols = batches).
__global__ __launch_bounds__(512, 2) void lstm_k(const ushort_t* __restrict__ xg,
                                                 const ushort_t* __restrict__ whh,
                                                 ushort_t* __restrict__ hglob,
                                                 int* __restrict__ cnt) {
    const int d = blockIdx.x >> 3;
    const int g = blockIdx.x & 7;
    const int tid = threadIdx.x;
    const int w = tid >> 6, lane = tid & 63;
    const int q = lane >> 4, m16 = lane & 15;
    const int hg = w >> 2;               // hu subgroup (0/1)
    const int bq = w & 3;                // batch quarter

    const int hu16 = g * 32 + hg * 16;          // m-tile base (weight rows)
    const int bl   = bq * 16 + m16;             // this lane's batch
    const int hub  = hu16 + q * 4;              // this lane's 4 hu (C rows)
    const ushort_t* wp = whh + (size_t)d * NG * NH;

    // Weight A-fragments, register-resident (atomic loads: not remat'able).
    // wreg[nt][ks]: row = nt*NH + hu16 + m16, k = ks*32 + q*8  (16B = 2x8B)
    short8 wreg[4][8];
    #pragma unroll
    for (int nt = 0; nt < 4; ++nt)
        #pragma unroll
        for (int ks = 0; ks < 8; ++ks) {
            const ushort_t* src = wp + (size_t)(nt * NH + hu16 + m16) * NH + ks * 32 + q * 8;
            union { ull_t u[2]; short8 s8; } uu;
            uu.u[0] = __hip_atomic_load((const ull_t*)(src),
                                        __ATOMIC_RELAXED, __HIP_MEMORY_SCOPE_AGENT);
            uu.u[1] = __hip_atomic_load((const ull_t*)(src + 4),
                                        __ATOMIC_RELAXED, __HIP_MEMORY_SCOPE_AGENT);
            wreg[nt][ks] = uu.s8;
        }

    float c[4] = {0.f, 0.f, 0.f, 0.f};
    ushort_t* hdir = hglob + (size_t)d * 513 * HSLOT;
    int* mycnt = cnt + d * NT;

    for (int s = 0; s < NT; ++s) {
        const int t = d ? (NT - 1 - s) : s;

        // xg prefetch: 4x8B contiguous (batch bl, cols d*NG+nt*NH+hub..+3)
        ull_t xraw[4];
        #pragma unroll
        for (int nt = 0; nt < 4; ++nt)
            xraw[nt] = *(const ull_t*)(xg + (size_t)(t * NB + bl) * NCC
                                       + d * NG + nt * NH + hub);

        if (s > 0) {
            while (__hip_atomic_load(&mycnt[s - 1], __ATOMIC_RELAXED,
                                     __HIP_MEMORY_SCOPE_AGENT) < NWAVES) {}
        }

        // B-frags: h_prev[n=batch bl][k], 16B contiguous via 2x8B atomics.
        const ushort_t* hprev = hdir + (size_t)s * HSLOT + bl * NH;
        short8 bf8[8];
        #pragma unroll
        for (int ks = 0; ks < 8; ++ks) {
            union { ull_t u[2]; short8 s8; } uu;
            uu.u[0] = __hip_atomic_load((const ull_t*)(hprev + ks * 32 + q * 8),
                                        __ATOMIC_RELAXED, __HIP_MEMORY_SCOPE_AGENT);
            uu.u[1] = __hip_atomic_load((const ull_t*)(hprev + ks * 32 + q * 8 + 4),
                                        __ATOMIC_RELAXED, __HIP_MEMORY_SCOPE_AGENT);
            bf8[ks] = uu.s8;
        }

        float gv[4][4];
        #pragma unroll
        for (int nt = 0; nt < 4; ++nt) {
            floatx4 acc = (floatx4){0.f, 0.f, 0.f, 0.f};
            #pragma unroll
            for (int ks = 0; ks < 8; ++ks)
                acc = __builtin_amdgcn_mfma_f32_16x16x32_bf16(wreg[nt][ks], bf8[ks], acc, 0, 0, 0);
            const ushort_t* xp = (const ushort_t*)&xraw[nt];
            #pragma unroll
            for (int r = 0; r < 4; ++r) gv[nt][r] = acc[r] + b2f(xp[r]);
        }

        ushort_t hb[4];
        #pragma unroll
        for (int r = 0; r < 4; ++r) {
            float ig = sigf(gv[0][r]);
            float fg = sigf(gv[1][r]);
            float gg = tanhfast(gv[2][r]);
            float og = sigf(gv[3][r]);
            c[r] = fg * c[r] + ig * gg;
            hb[r] = f2b(og * tanhfast(c[r]));
        }
        // one 8B write-through store: h[bl][hub..hub+3]
        __hip_atomic_store((ull_t*)(hdir + (size_t)(s + 1) * HSLOT + bl * NH + hub),
                           *(const ull_t*)hb, __ATOMIC_RELAXED, __HIP_MEMORY_SCOPE_AGENT);
        asm volatile("s_waitcnt vmcnt(0)" ::: "memory");   // store at coherence pt
        if (lane == 0)
            __hip_atomic_fetch_add(&mycnt[s], 1, __ATOMIC_RELAXED,
                                   __HIP_MEMORY_SCOPE_AGENT);
    }
}

// ---------------- K4: em[t,b,l] = feats . W_lin[l] + b_lin ------------------
// fwd h(t) = hglob slot t+1 (dir0); bwd h(t) = hglob slot 512-t (dir1)
__global__ void em_k(const ushort_t* __restrict__ hglob, const float* __restrict__ Wlin,
                     const float* __restrict__ blin, float* __restrict__ em) {
    const int t = blockIdx.x;
    const int tid = threadIdx.x;          // 576 threads
    __shared__ float Ws[NL * 520];
    for (int idx = tid; idx < NL * 2 * NH; idx += 576) {
        int l = idx >> 9, k = idx & 511;
        Ws[l * 520 + k] = Wlin[l * 2 * NH + k];
    }
    __syncthreads();
    const int b = tid / NL, l = tid - b * NL;
    const ushort_t* hf = hglob + (size_t)(t + 1) * HSLOT + (size_t)b * NH;
    const ushort_t* hb = hglob + ((size_t)513 + (512 - t)) * HSLOT + (size_t)b * NH;
    float acc = blin[l];
    #pragma unroll 4
    for (int kc = 0; kc < NH / 8; ++kc) {
        uint4 u = *(const uint4*)(hf + kc * 8);
        const uint_t* uu = (const uint_t*)&u;
        #pragma unroll
        for (int j = 0; j < 4; ++j) {
            acc += b2f((ushort_t)(uu[j] & 0xFFFF)) * Ws[l * 520 + kc * 8 + 2 * j];
            acc += b2f((ushort_t)(uu[j] >> 16))    * Ws[l * 520 + kc * 8 + 2 * j + 1];
        }
    }
    #pragma unroll 4
    for (int kc = 0; kc < NH / 8; ++kc) {
        uint4 u = *(const uint4*)(hb + kc * 8);
        const uint_t* uu = (const uint_t*)&u;
        #pragma unroll
        for (int j = 0; j < 4; ++j) {
            acc += b2f((ushort_t)(uu[j] & 0xFFFF)) * Ws[l * 520 + NH + kc * 8 + 2 * j];
            acc += b2f((ushort_t)(uu[j] >> 16))    * Ws[l * 520 + NH + kc * 8 + 2 * j + 1];
        }
    }
    em[((size_t)t * NB + b) * NL + l] = acc;
}

// ---------------- K5: CRF numerator per batch (parallel over t) -------------
__global__ void num_k(const float* __restrict__ em, const int* __restrict__ mask,
                      const int* __restrict__ labels, const float* __restrict__ start,
                      const float* __restrict__ endt, const float* __restrict__ trans,
                      float* __restrict__ numbuf) {
    const int b = blockIdx.x;       // 64 blocks x 64 threads (1 wave)
    const int lane = threadIdx.x;
    int cntm = 0;
    for (int t = lane; t < NT; t += 64) cntm += (mask[b * NT + t] != 0);
    #pragma unroll
    for (int off = 32; off > 0; off >>= 1) cntm += __shfl_down(cntm, off);
    const int len = __shfl(cntm, 0);

    float part = 0.f;
    for (int t = lane; t < NT; t += 64) {
        if (t >= 1 && t < len) {
            int tp = labels[b * NT + t - 1];
            int tg = labels[b * NT + t];
            part += trans[tp * NL + tg] + em[((size_t)t * NB + b) * NL + tg];
        }
    }
    #pragma unroll
    for (int off = 32; off > 0; off >>= 1) part += __shfl_down(part, off);
    if (lane == 0) {
        int tag0 = labels[b * NT];
        float num = part + start[tag0] + em[(size_t)b * NL + tag0]
                  + endt[labels[b * NT + len - 1]];
        numbuf[b] = num;
    }
}

// ---------------- K6: CRF forward (logZ), diff = logZ - num -----------------
__global__ void crf_k(const float* __restrict__ em, const int* __restrict__ mask,
                      const float* __restrict__ start, const float* __restrict__ endt,
                      const float* __restrict__ trans, const float* __restrict__ numbuf,
                      float* __restrict__ diff) {
    const int b = blockIdx.x;
    const int lane = threadIdx.x;       // 64 threads = 1 wave
    int cnt = 0;
    for (int t = lane; t < NT; t += 64) cnt += (mask[b * NT + t] != 0);
    #pragma unroll
    for (int off = 32; off > 0; off >>= 1) cnt += __shfl_down(cnt, off);
    const int len = __shfl(cnt, 0);

    float tcol[NL];
    #pragma unroll
    for (int i = 0; i < NL; ++i) tcol[i] = (lane < NL) ? trans[i * NL + lane] : 0.f;
    float endv = (lane < NL) ? endt[lane] : 0.f;
    float score = (lane < NL) ? start[lane] + em[(size_t)b * NL + lane] : -1e30f;

    for (int t = 1; t < len; ++t) {
        float emv = (lane < NL) ? em[((size_t)t * NB + b) * NL + lane] : 0.f;
        float sv[NL];
        #pragma unroll
        for (int i = 0; i < NL; ++i) sv[i] = __shfl(score, i) + tcol[i];
        float m = sv[0];
        #pragma unroll
        for (int i = 1; i < NL; ++i) m = fmaxf(m, sv[i]);
        float sum = 0.f;
        #pragma unroll
        for (int i = 0; i < NL; ++i) sum += __expf(sv[i] - m);
        float nxt = m + __logf(sum) + emv;
        if (lane < NL) score = nxt;
    }
    float v = (lane < NL) ? score + endv : -1e30f;
    float m = -1e30f;
    float sv[NL];
    #pragma unroll
    for (int i = 0; i < NL; ++i) { sv[i] = __shfl(v, i); m = fmaxf(m, sv[i]); }
    float sum = 0.f;
    #pragma unroll
    for (int i = 0; i < NL; ++i) sum += __expf(sv[i] - m);
    float logZ = m + __logf(sum);
    if (lane == 0) diff[b] = logZ - numbuf[b];
}

// ---------------- K7: mean over batch -> d_out ------------------------------
__global__ void final_k(const float* __restrict__ diff, float* __restrict__ out) {
    float v = diff[threadIdx.x];
    #pragma unroll
    for (int off = 32; off > 0; off >>= 1) v += __shfl_down(v, off);
    if (threadIdx.x == 0) out[0] = v * (1.0f / NB);
}

extern "C" void kernel_launch(void* const* d_in, const int* in_sizes, int n_in,
                              void* d_out, int out_size, void* d_ws, size_t ws_size,
                              hipStream_t stream) {
    const float* emb   = (const float*)d_in[0];
    const float* Wihf  = (const float*)d_in[1];
    const float* Whhf  = (const float*)d_in[2];
    const float* bf    = (const float*)d_in[3];
    const float* Wihb  = (const float*)d_in[4];
    const float* Whhb  = (const float*)d_in[5];
    const float* bb    = (const float*)d_in[6];
    const float* Wlin  = (const float*)d_in[7];
    const float* blin  = (const float*)d_in[8];
    const float* start = (const float*)d_in[9];
    const float* endt  = (const float*)d_in[10];
    const float* trans = (const float*)d_in[11];
    const int*   mask  = (const int*)d_in[12];
    const int*   labels= (const int*)d_in[13];

    char* ws = (char*)d_ws;
    ushort_t* xbf   = (ushort_t*)(ws + 0);                     // 50,331,648
    ushort_t* wcat  = (ushort_t*)(ws + 50331648);              //  3,145,728
    ushort_t* whhbf = (ushort_t*)(ws + 53477376);              //  1,048,576
    float*    bias  = (float*)   (ws + 54525952);              //      8,192
    ushort_t* xg    = (ushort_t*)(ws + 54534144);              // 134,217,728
    ushort_t* hglob = (ushort_t*)(ws + 188751872);             // 33,619,968
    float*    em    = (float*)   (ws + 222371840);             //  1,179,648
    float*    numb  = (float*)   (ws + 223551488);             //        256
    float*    diff  = (float*)   (ws + 223551744);             //        256
    int*      cnt   = (int*)     (ws + 223552000);             //      4,096

    zero_k<<<4, 256, 0, stream>>>(cnt, hglob);
    conv_x<<<NT * NB * (NE / 4) / 256, 256, 0, stream>>>(emb, xbf);
    conv_w<<<(NCC * NE + 2 * NG * NH + NCC) / 256, 256, 0, stream>>>(
        Wihf, Wihb, Whhf, Whhb, bf, bb, wcat, whhbf, bias);
    gemm_xg<<<dim3(NCC / 128, NT * NB / 128), 256, 0, stream>>>(xbf, wcat, bias, xg);
    lstm_k<<<16, 512, 0, stream>>>(xg, whhbf, hglob, cnt);
    em_k<<<NT, 576, 0, stream>>>(hglob, Wlin, blin, em);
    num_k<<<NB, 64, 0, stream>>>(em, mask, labels, start, endt, trans, numb);
    crf_k<<<NB, 64, 0, stream>>>(em, mask, start, endt, trans, numb, diff);
    final_k<<<1, 64, 0, stream>>>(diff, (float*)d_out);
}

// Round 5
// 2903.076 us; speedup vs baseline: 1.6876x; 1.6876x over previous
//
#include <hip/hip_runtime.h>
#include <hip/hip_bf16.h>
#include <cstdint>
#include <cstddef>

// B=64 T=512 E=768 H=256 L=9.  BiLSTM + linear + CRF loglik (scalar out).
// R5: recurrence with ZERO inter-WG sync. 8 WGs = 2 dirs x 4 batch-groups
// of 16; each WG holds its direction's FULL W_hh in fp8 across the register
// file (8 waves x 64 lanes x 128 VGPR x 4B = 256 KB), pinned via asm. h is
// LDS-resident fp8 (double buffer, 1 barrier/step). Gate rows interleaved
// (row' = hu*4 + gate) so each lane's C-frag = all 4 gates of one hu.

typedef __attribute__((ext_vector_type(8))) short short8;
typedef __attribute__((ext_vector_type(4))) float floatx4;
typedef unsigned short ushort_t;
typedef unsigned char uchar_t;
typedef unsigned int uint_t;
typedef unsigned long long ull_t;

#define NB   64
#define NT   512
#define NE   768
#define NH   256
#define NL   9
#define NG   1024   // 4*H
#define NCC  2048   // both dirs' gates
#define HPAD 264    // LDS h row stride (bytes, fp8), 8B-aligned

__device__ inline float b2f(ushort_t u) {
    union { uint_t i; float f; } v; v.i = ((uint_t)u) << 16; return v.f;
}
__device__ inline ushort_t f2b(float f) {
    union { float f; uint_t i; } v; v.f = f;
    uint_t r = (v.i + 0x7FFFu + ((v.i >> 16) & 1u)) >> 16;
    return (ushort_t)r;
}
__device__ inline float sigf(float x) { return 1.0f / (1.0f + __expf(-x)); }
__device__ inline float tanhfast(float x) { return 1.0f - 2.0f / (1.0f + __expf(2.0f * x)); }

// ---------------- K1: embeddings (B,T,E) f32 -> xbf (T,B,E) bf16 ------------
__global__ void conv_x(const float* __restrict__ emb, ushort_t* __restrict__ xbf) {
    int id = blockIdx.x * blockDim.x + threadIdx.x;      // over T*B*(E/4)
    int t  = id / (NB * (NE / 4));
    int rm = id - t * (NB * (NE / 4));
    int b  = rm / (NE / 4);
    int e4 = rm - b * (NE / 4);
    const float4 v = *(const float4*)(emb + ((size_t)b * NT + t) * NE + e4 * 4);
    ushort_t o[4] = { f2b(v.x), f2b(v.y), f2b(v.z), f2b(v.w) };
    *(uint2*)(xbf + ((size_t)t * NB + b) * NE + e4 * 4) = *(const uint2*)o;
}

// ---------------- K1b: weights. Row interleave: row' = d*1024 + hu*4 + gate -
// wcat (bf16, for xg GEMM), whh8 (fp8 e4m3), bias (f32), all in row' order.
__global__ void conv_w(const float* __restrict__ Wihf, const float* __restrict__ Wihb,
                       const float* __restrict__ Whhf, const float* __restrict__ Whhb,
                       const float* __restrict__ bf,   const float* __restrict__ bb,
                       ushort_t* __restrict__ wcat, uchar_t* __restrict__ whh8,
                       float* __restrict__ bias) {
    int idx = blockIdx.x * blockDim.x + threadIdx.x;
    const int NW1 = NCC * NE;            // 1572864
    const int NW2 = NCC * NH / 2;        // 262144 fp8 pairs
    if (idx < NW1) {
        int rowp = idx / NE, col = idx - rowp * NE;
        int d = rowp >> 10, rr = rowp & 1023;
        int hu = rr >> 2, gate = rr & 3;
        const float* W = d ? Wihb : Wihf;
        wcat[idx] = f2b(W[(size_t)(gate * NH + hu) * NE + col]);
    } else if (idx < NW1 + NW2) {
        int j = idx - NW1;
        int rowp = j >> 7, kp = (j & 127) * 2;
        int d = rowp >> 10, rr = rowp & 1023;
        int hu = rr >> 2, gate = rr & 3;
        const float* W = d ? Whhb : Whhf;
        float f0 = W[(size_t)(gate * NH + hu) * NH + kp];
        float f1 = W[(size_t)(gate * NH + hu) * NH + kp + 1];
        uint_t pk = __builtin_amdgcn_cvt_pk_fp8_f32(f0, f1, 0, false);
        *(ushort_t*)(whh8 + (size_t)rowp * NH + kp) = (ushort_t)(pk & 0xFFFF);
    } else if (idx < NW1 + NW2 + NCC) {
        int rowp = idx - NW1 - NW2;
        int d = rowp >> 10, rr = rowp & 1023;
        int hu = rr >> 2, gate = rr & 3;
        bias[rowp] = (d ? bb : bf)[gate * NH + hu];
    }
}

// ---------------- K2: xg = xbf(32768x768) @ wcat^T(2048x768) + bias ---------
__global__ __launch_bounds__(256) void gemm_xg(const ushort_t* __restrict__ A,
                                               const ushort_t* __restrict__ W,
                                               const float* __restrict__ bias,
                                               ushort_t* __restrict__ C) {
    __shared__ ushort_t As[128 * 72];
    __shared__ ushort_t Bs[128 * 72];
    const int tid = threadIdx.x;
    const int wave = tid >> 6, lane = tid & 63;
    const int q = lane >> 4, m16 = lane & 15;
    const int wm = wave & 1, wn = wave >> 1;
    const int m0 = blockIdx.y * 128, n0 = blockIdx.x * 128;

    floatx4 acc[4][4];
    #pragma unroll
    for (int i = 0; i < 4; ++i)
        #pragma unroll
        for (int j = 0; j < 4; ++j) acc[i][j] = (floatx4){0.f, 0.f, 0.f, 0.f};

    for (int kt = 0; kt < NE / 64; ++kt) {
        __syncthreads();
        #pragma unroll
        for (int it = 0; it < 4; ++it) {
            int chunk = tid + it * 256;         // 0..1023
            int row = chunk >> 3, kc = chunk & 7;
            *(uint4*)(&As[row * 72 + kc * 8]) =
                *(const uint4*)(A + (size_t)(m0 + row) * NE + kt * 64 + kc * 8);
            *(uint4*)(&Bs[row * 72 + kc * 8]) =
                *(const uint4*)(W + (size_t)(n0 + row) * NE + kt * 64 + kc * 8);
        }
        __syncthreads();
        #pragma unroll
        for (int ks = 0; ks < 2; ++ks) {
            short8 af[4], bfr[4];
            #pragma unroll
            for (int mt = 0; mt < 4; ++mt)
                af[mt] = *(const short8*)(&As[(wm * 64 + mt * 16 + m16) * 72 + ks * 32 + q * 8]);
            #pragma unroll
            for (int nt = 0; nt < 4; ++nt)
                bfr[nt] = *(const short8*)(&Bs[(wn * 64 + nt * 16 + m16) * 72 + ks * 32 + q * 8]);
            #pragma unroll
            for (int mt = 0; mt < 4; ++mt)
                #pragma unroll
                for (int nt = 0; nt < 4; ++nt)
                    acc[mt][nt] = __builtin_amdgcn_mfma_f32_16x16x32_bf16(
                        af[mt], bfr[nt], acc[mt][nt], 0, 0, 0);
        }
    }
    float bcol[4];
    #pragma unroll
    for (int nt = 0; nt < 4; ++nt) bcol[nt] = bias[n0 + wn * 64 + nt * 16 + m16];
    #pragma unroll
    for (int mt = 0; mt < 4; ++mt)
        #pragma unroll
        for (int nt = 0; nt < 4; ++nt) {
            int gn = n0 + wn * 64 + nt * 16 + m16;
            #pragma unroll
            for (int r = 0; r < 4; ++r) {
                int gm = m0 + wm * 64 + mt * 16 + q * 4 + r;
                C[(size_t)gm * NCC + gn] = f2b(acc[mt][nt][r] + bcol[nt]);
            }
        }
}

// ---------------- K3: recurrence, 8 WGs = 2 dirs x 4 batch-groups -----------
// 512 threads = 8 waves; wave w owns gate rows' [w*128, w*128+128) = hu
// [w*32, w*32+32) x 4 gates. Weights fp8 in 128 VGPRs/lane (asm-pinned).
// h: LDS fp8 double buffer. Lane (q,m16) of wave w: batch = bg*16+m16,
// C-frag reg r of m-tile mt = gate r of hu (w*32+mt*4+q).
__global__ __launch_bounds__(512, 2) void lstm_k(const ushort_t* __restrict__ xg,
                                                 const uchar_t* __restrict__ whh8,
                                                 ushort_t* __restrict__ hhist) {
    const int d  = blockIdx.x >> 2;
    const int bg = blockIdx.x & 3;
    const int tid = threadIdx.x;
    const int w = tid >> 6, lane = tid & 63;
    const int q = lane >> 4, m16 = lane & 15;
    const int bl = bg * 16 + m16;               // this lane's batch

    __shared__ uchar_t hb8[2][16 * HPAD];       // fp8 h, [batch][hu]
    for (int i = tid; i < 16 * HPAD; i += 512) hb8[0][i] = 0;

    // Register-resident W_hh slice (fp8): wregu[mt][ks] = A-frag 8 bytes,
    // rows' w*128+mt*16+m16, k = ks*32+q*8.
    const uchar_t* wp = whh8 + (size_t)(d * NG + w * 128) * NH;
    ull_t wregu[8][8];
    #pragma unroll
    for (int mt = 0; mt < 8; ++mt)
        #pragma unroll
        for (int ks = 0; ks < 8; ++ks)
            wregu[mt][ks] = *(const ull_t*)(wp + (size_t)(mt * 16 + m16) * NH + ks * 32 + q * 8);
    #pragma unroll
    for (int mt = 0; mt < 8; ++mt)
        #pragma unroll
        for (int ks = 0; ks < 8; ++ks)
            asm volatile("" : "+v"(wregu[mt][ks]));   // pin: defeat remat/sink

    float c[8];
    #pragma unroll
    for (int i = 0; i < 8; ++i) c[i] = 0.f;
    __syncthreads();

    #pragma unroll 1
    for (int s = 0; s < NT; ++s) {
        const int t = d ? (NT - 1 - s) : s;

        // xg: 8B per m-tile (4 gates of one hu), issue all early.
        const ushort_t* xp = xg + (size_t)(t * NB + bl) * NCC + d * NG + w * 128;
        ull_t xr[8];
        #pragma unroll
        for (int mt = 0; mt < 8; ++mt)
            xr[mt] = *(const ull_t*)(xp + mt * 16 + q * 4);

        // B-frags: h_prev fp8 from LDS, 8B per k-chunk, shared across mt.
        const uchar_t* hrow = &hb8[s & 1][m16 * HPAD];
        ull_t hf[8];
        #pragma unroll
        for (int ks = 0; ks < 8; ++ks)
            hf[ks] = *(const ull_t*)(hrow + ks * 32 + q * 8);

        floatx4 acc[8];
        #pragma unroll
        for (int mt = 0; mt < 8; ++mt) acc[mt] = (floatx4){0.f, 0.f, 0.f, 0.f};
        #pragma unroll
        for (int ks = 0; ks < 8; ++ks)
            #pragma unroll
            for (int mt = 0; mt < 8; ++mt)
                acc[mt] = __builtin_amdgcn_mfma_f32_16x16x32_fp8_fp8(
                    (long)wregu[mt][ks], (long)hf[ks], acc[mt], 0, 0, 0);

        // Epilogue: all 4 gates in-lane; h -> hhist (bf16) + LDS (fp8).
        float hv[8];
        uchar_t* hwr = &hb8[(s + 1) & 1][m16 * HPAD];
        ushort_t* hh = hhist + ((size_t)(d * NT + t) * NB + bl) * NH + w * 32;
        #pragma unroll
        for (int mt = 0; mt < 8; ++mt) {
            const ushort_t* xv = (const ushort_t*)&xr[mt];
            float ig = sigf(acc[mt][0] + b2f(xv[0]));
            float fg = sigf(acc[mt][1] + b2f(xv[1]));
            float gg = tanhfast(acc[mt][2] + b2f(xv[2]));
            float og = sigf(acc[mt][3] + b2f(xv[3]));
            c[mt] = fg * c[mt] + ig * gg;
            float h = og * tanhfast(c[mt]);
            hv[mt] = h;
            hh[mt * 4 + q] = f2b(h);
        }
        #pragma unroll
        for (int p = 0; p < 4; ++p) {
            uint_t pk = __builtin_amdgcn_cvt_pk_fp8_f32(hv[2 * p], hv[2 * p + 1], 0, false);
            hwr[w * 32 + (2 * p) * 4 + q]     = (uchar_t)(pk & 0xFF);
            hwr[w * 32 + (2 * p + 1) * 4 + q] = (uchar_t)((pk >> 8) & 0xFF);
        }
        __syncthreads();
    }
}

// ---------------- K4: em[t,b,l] = feats . W_lin[l] + b_lin ------------------
__global__ void em_k(const ushort_t* __restrict__ hhist, const float* __restrict__ Wlin,
                     const float* __restrict__ blin, float* __restrict__ em) {
    const int t = blockIdx.x;
    const int tid = threadIdx.x;          // 576 threads
    __shared__ float Ws[NL * 520];
    for (int idx = tid; idx < NL * 2 * NH; idx += 576) {
        int l = idx >> 9, k = idx & 511;
        Ws[l * 520 + k] = Wlin[l * 2 * NH + k];
    }
    __syncthreads();
    const int b = tid / NL, l = tid - b * NL;
    const ushort_t* hf = hhist + ((size_t)t * NB + b) * NH;
    const ushort_t* hb = hhist + ((size_t)(NT + t) * NB + b) * NH;
    float acc = blin[l];
    #pragma unroll 4
    for (int kc = 0; kc < NH / 8; ++kc) {
        uint4 u = *(const uint4*)(hf + kc * 8);
        const uint_t* uu = (const uint_t*)&u;
        #pragma unroll
        for (int j = 0; j < 4; ++j) {
            acc += b2f((ushort_t)(uu[j] & 0xFFFF)) * Ws[l * 520 + kc * 8 + 2 * j];
            acc += b2f((ushort_t)(uu[j] >> 16))    * Ws[l * 520 + kc * 8 + 2 * j + 1];
        }
    }
    #pragma unroll 4
    for (int kc = 0; kc < NH / 8; ++kc) {
        uint4 u = *(const uint4*)(hb + kc * 8);
        const uint_t* uu = (const uint_t*)&u;
        #pragma unroll
        for (int j = 0; j < 4; ++j) {
            acc += b2f((ushort_t)(uu[j] & 0xFFFF)) * Ws[l * 520 + NH + kc * 8 + 2 * j];
            acc += b2f((ushort_t)(uu[j] >> 16))    * Ws[l * 520 + NH + kc * 8 + 2 * j + 1];
        }
    }
    em[((size_t)t * NB + b) * NL + l] = acc;
}

// ---------------- K5: CRF numerator per batch (parallel over t) -------------
__global__ void num_k(const float* __restrict__ em, const int* __restrict__ mask,
                      const int* __restrict__ labels, const float* __restrict__ start,
                      const float* __restrict__ endt, const float* __restrict__ trans,
                      float* __restrict__ numbuf) {
    const int b = blockIdx.x;       // 64 blocks x 64 threads (1 wave)
    const int lane = threadIdx.x;
    int cntm = 0;
    for (int t = lane; t < NT; t += 64) cntm += (mask[b * NT + t] != 0);
    #pragma unroll
    for (int off = 32; off > 0; off >>= 1) cntm += __shfl_down(cntm, off);
    const int len = __shfl(cntm, 0);

    float part = 0.f;
    for (int t = lane; t < NT; t += 64) {
        if (t >= 1 && t < len) {
            int tp = labels[b * NT + t - 1];
            int tg = labels[b * NT + t];
            part += trans[tp * NL + tg] + em[((size_t)t * NB + b) * NL + tg];
        }
    }
    #pragma unroll
    for (int off = 32; off > 0; off >>= 1) part += __shfl_down(part, off);
    if (lane == 0) {
        int tag0 = labels[b * NT];
        numbuf[b] = part + start[tag0] + em[(size_t)b * NL + tag0]
                  + endt[labels[b * NT + len - 1]];
    }
}

// ---------------- K6: CRF forward (logZ), diff = logZ - num -----------------
__global__ void crf_k(const float* __restrict__ em, const int* __restrict__ mask,
                      const float* __restrict__ start, const float* __restrict__ endt,
                      const float* __restrict__ trans, const float* __restrict__ numbuf,
                      float* __restrict__ diff) {
    const int b = blockIdx.x;
    const int lane = threadIdx.x;       // 64 threads = 1 wave
    int cnt = 0;
    for (int t = lane; t < NT; t += 64) cnt += (mask[b * NT + t] != 0);
    #pragma unroll
    for (int off = 32; off > 0; off >>= 1) cnt += __shfl_down(cnt, off);
    const int len = __shfl(cnt, 0);

    float tcol[NL];
    #pragma unroll
    for (int i = 0; i < NL; ++i) tcol[i] = (lane < NL) ? trans[i * NL + lane] : 0.f;
    float endv = (lane < NL) ? endt[lane] : 0.f;
    float score = (lane < NL) ? start[lane] + em[(size_t)b * NL + lane] : -1e30f;

    for (int t = 1; t < len; ++t) {
        float emv = (lane < NL) ? em[((size_t)t * NB + b) * NL + lane] : 0.f;
        float sv[NL];
        #pragma unroll
        for (int i = 0; i < NL; ++i) sv[i] = __shfl(score, i) + tcol[i];
        float m = sv[0];
        #pragma unroll
        for (int i = 1; i < NL; ++i) m = fmaxf(m, sv[i]);
        float sum = 0.f;
        #pragma unroll
        for (int i = 0; i < NL; ++i) sum += __expf(sv[i] - m);
        float nxt = m + __logf(sum) + emv;
        if (lane < NL) score = nxt;
    }
    float v = (lane < NL) ? score + endv : -1e30f;
    float m = -1e30f;
    float sv[NL];
    #pragma unroll
    for (int i = 0; i < NL; ++i) { sv[i] = __shfl(v, i); m = fmaxf(m, sv[i]); }
    float sum = 0.f;
    #pragma unroll
    for (int i = 0; i < NL; ++i) sum += __expf(sv[i] - m);
    float logZ = m + __logf(sum);
    if (lane == 0) diff[b] = logZ - numbuf[b];
}

// ---------------- K7: mean over batch -> d_out ------------------------------
__global__ void final_k(const float* __restrict__ diff, float* __restrict__ out) {
    float v = diff[threadIdx.x];
    #pragma unroll
    for (int off = 32; off > 0; off >>= 1) v += __shfl_down(v, off);
    if (threadIdx.x == 0) out[0] = v * (1.0f / NB);
}

extern "C" void kernel_launch(void* const* d_in, const int* in_sizes, int n_in,
                              void* d_out, int out_size, void* d_ws, size_t ws_size,
                              hipStream_t stream) {
    const float* emb   = (const float*)d_in[0];
    const float* Wihf  = (const float*)d_in[1];
    const float* Whhf  = (const float*)d_in[2];
    const float* bf    = (const float*)d_in[3];
    const float* Wihb  = (const float*)d_in[4];
    const float* Whhb  = (const float*)d_in[5];
    const float* bb    = (const float*)d_in[6];
    const float* Wlin  = (const float*)d_in[7];
    const float* blin  = (const float*)d_in[8];
    const float* start = (const float*)d_in[9];
    const float* endt  = (const float*)d_in[10];
    const float* trans = (const float*)d_in[11];
    const int*   mask  = (const int*)d_in[12];
    const int*   labels= (const int*)d_in[13];

    char* ws = (char*)d_ws;
    ushort_t* xbf   = (ushort_t*)(ws + 0);                     // 50,331,648
    ushort_t* wcat  = (ushort_t*)(ws + 50331648);              //  3,145,728
    uchar_t*  whh8  = (uchar_t*) (ws + 53477376);              //    524,288
    float*    bias  = (float*)   (ws + 54001664);              //      8,192
    ushort_t* xg    = (ushort_t*)(ws + 54009856);              // 134,217,728
    ushort_t* hhist = (ushort_t*)(ws + 188227584);             // 33,554,432
    float*    em    = (float*)   (ws + 221782016);             //  1,179,648
    float*    numb  = (float*)   (ws + 222961664);             //        256
    float*    diff  = (float*)   (ws + 222961920);             //        256

    conv_x<<<NT * NB * (NE / 4) / 256, 256, 0, stream>>>(emb, xbf);
    conv_w<<<(NCC * NE + NCC * NH / 2 + NCC) / 256, 256, 0, stream>>>(
        Wihf, Wihb, Whhf, Whhb, bf, bb, wcat, whh8, bias);
    gemm_xg<<<dim3(NCC / 128, NT * NB / 128), 256, 0, stream>>>(xbf, wcat, bias, xg);
    lstm_k<<<8, 512, 0, stream>>>(xg, whh8, hhist);
    em_k<<<NT, 576, 0, stream>>>(hhist, Wlin, blin, em);
    num_k<<<NB, 64, 0, stream>>>(em, mask, labels, start, endt, trans, numb);
    crf_k<<<NB, 64, 0, stream>>>(em, mask, start, endt, trans, numb, diff);
    final_k<<<1, 64, 0, stream>>>(diff, (float*)d_out);
}

// Round 6
// 2436.248 us; speedup vs baseline: 2.0109x; 1.1916x over previous
//
#include <hip/hip_runtime.h>
#include <hip/hip_bf16.h>
#include <cstdint>
#include <cstddef>

// B=64 T=512 E=768 H=256 L=9.  BiLSTM + linear + CRF loglik (scalar out).
// R6: R5 structure (8 WGs = 2 dirs x 4 batch-groups, zero inter-WG sync,
// fp8 W_hh register-resident, h in LDS double buffer) with:
//  - MX-scaled MFMA 16x16x128 f8f6f4, unit scales (2.25x rate, 4x fewer inst)
//  - weights pinned in AGPRs via "+a" asm (no remat/sink ambiguity)
//  - h history stored fp8 via coalesced LDS->global copy (kills the 2B
//    scattered bf16 stores that the per-step vmcnt(0) had to drain)

typedef __attribute__((ext_vector_type(8))) short short8;
typedef __attribute__((ext_vector_type(4))) float floatx4;
typedef __attribute__((ext_vector_type(2))) float floatx2;
typedef __attribute__((ext_vector_type(8))) int v8i;
typedef unsigned short ushort_t;
typedef unsigned char uchar_t;
typedef unsigned int uint_t;
typedef unsigned long long ull_t;

#define NB   64
#define NT   512
#define NE   768
#define NH   256
#define NL   9
#define NG   1024   // 4*H
#define NCC  2048   // both dirs' gates
#define HPAD 272    // LDS h row stride (bytes, fp8): 17x16B -> 16B-aligned rows

__device__ inline float b2f(ushort_t u) {
    union { uint_t i; float f; } v; v.i = ((uint_t)u) << 16; return v.f;
}
__device__ inline ushort_t f2b(float f) {
    union { float f; uint_t i; } v; v.f = f;
    uint_t r = (v.i + 0x7FFFu + ((v.i >> 16) & 1u)) >> 16;
    return (ushort_t)r;
}
__device__ inline float sigf(float x) { return 1.0f / (1.0f + __expf(-x)); }
__device__ inline float tanhfast(float x) { return 1.0f - 2.0f / (1.0f + __expf(2.0f * x)); }

// ---------------- K1: embeddings (B,T,E) f32 -> xbf (T,B,E) bf16 ------------
__global__ void conv_x(const float* __restrict__ emb, ushort_t* __restrict__ xbf) {
    int id = blockIdx.x * blockDim.x + threadIdx.x;      // over T*B*(E/4)
    int t  = id / (NB * (NE / 4));
    int rm = id - t * (NB * (NE / 4));
    int b  = rm / (NE / 4);
    int e4 = rm - b * (NE / 4);
    const float4 v = *(const float4*)(emb + ((size_t)b * NT + t) * NE + e4 * 4);
    ushort_t o[4] = { f2b(v.x), f2b(v.y), f2b(v.z), f2b(v.w) };
    *(uint2*)(xbf + ((size_t)t * NB + b) * NE + e4 * 4) = *(const uint2*)o;
}

// ---------------- K1b: weights. Row interleave: row' = d*1024 + hu*4 + gate -
__global__ void conv_w(const float* __restrict__ Wihf, const float* __restrict__ Wihb,
                       const float* __restrict__ Whhf, const float* __restrict__ Whhb,
                       const float* __restrict__ bf,   const float* __restrict__ bb,
                       ushort_t* __restrict__ wcat, uchar_t* __restrict__ whh8,
                       float* __restrict__ bias) {
    int idx = blockIdx.x * blockDim.x + threadIdx.x;
    const int NW1 = NCC * NE;            // 1572864
    const int NW2 = NCC * NH / 2;        // 262144 fp8 pairs
    if (idx < NW1) {
        int rowp = idx / NE, col = idx - rowp * NE;
        int d = rowp >> 10, rr = rowp & 1023;
        int hu = rr >> 2, gate = rr & 3;
        const float* W = d ? Wihb : Wihf;
        wcat[idx] = f2b(W[(size_t)(gate * NH + hu) * NE + col]);
    } else if (idx < NW1 + NW2) {
        int j = idx - NW1;
        int rowp = j >> 7, kp = (j & 127) * 2;
        int d = rowp >> 10, rr = rowp & 1023;
        int hu = rr >> 2, gate = rr & 3;
        const float* W = d ? Whhb : Whhf;
        float f0 = W[(size_t)(gate * NH + hu) * NH + kp];
        float f1 = W[(size_t)(gate * NH + hu) * NH + kp + 1];
        uint_t pk = __builtin_amdgcn_cvt_pk_fp8_f32(f0, f1, 0, false);
        *(ushort_t*)(whh8 + (size_t)rowp * NH + kp) = (ushort_t)(pk & 0xFFFF);
    } else if (idx < NW1 + NW2 + NCC) {
        int rowp = idx - NW1 - NW2;
        int d = rowp >> 10, rr = rowp & 1023;
        int hu = rr >> 2, gate = rr & 3;
        bias[rowp] = (d ? bb : bf)[gate * NH + hu];
    }
}

// ---------------- K2: xg = xbf(32768x768) @ wcat^T(2048x768) + bias ---------
__global__ __launch_bounds__(256) void gemm_xg(const ushort_t* __restrict__ A,
                                               const ushort_t* __restrict__ W,
                                               const float* __restrict__ bias,
                                               ushort_t* __restrict__ C) {
    __shared__ ushort_t As[128 * 72];
    __shared__ ushort_t Bs[128 * 72];
    const int tid = threadIdx.x;
    const int wave = tid >> 6, lane = tid & 63;
    const int q = lane >> 4, m16 = lane & 15;
    const int wm = wave & 1, wn = wave >> 1;
    const int m0 = blockIdx.y * 128, n0 = blockIdx.x * 128;

    floatx4 acc[4][4];
    #pragma unroll
    for (int i = 0; i < 4; ++i)
        #pragma unroll
        for (int j = 0; j < 4; ++j) acc[i][j] = (floatx4){0.f, 0.f, 0.f, 0.f};

    for (int kt = 0; kt < NE / 64; ++kt) {
        __syncthreads();
        #pragma unroll
        for (int it = 0; it < 4; ++it) {
            int chunk = tid + it * 256;         // 0..1023
            int row = chunk >> 3, kc = chunk & 7;
            *(uint4*)(&As[row * 72 + kc * 8]) =
                *(const uint4*)(A + (size_t)(m0 + row) * NE + kt * 64 + kc * 8);
            *(uint4*)(&Bs[row * 72 + kc * 8]) =
                *(const uint4*)(W + (size_t)(n0 + row) * NE + kt * 64 + kc * 8);
        }
        __syncthreads();
        #pragma unroll
        for (int ks = 0; ks < 2; ++ks) {
            short8 af[4], bfr[4];
            #pragma unroll
            for (int mt = 0; mt < 4; ++mt)
                af[mt] = *(const short8*)(&As[(wm * 64 + mt * 16 + m16) * 72 + ks * 32 + q * 8]);
            #pragma unroll
            for (int nt = 0; nt < 4; ++nt)
                bfr[nt] = *(const short8*)(&Bs[(wn * 64 + nt * 16 + m16) * 72 + ks * 32 + q * 8]);
            #pragma unroll
            for (int mt = 0; mt < 4; ++mt)
                #pragma unroll
                for (int nt = 0; nt < 4; ++nt)
                    acc[mt][nt] = __builtin_amdgcn_mfma_f32_16x16x32_bf16(
                        af[mt], bfr[nt], acc[mt][nt], 0, 0, 0);
        }
    }
    float bcol[4];
    #pragma unroll
    for (int nt = 0; nt < 4; ++nt) bcol[nt] = bias[n0 + wn * 64 + nt * 16 + m16];
    #pragma unroll
    for (int mt = 0; mt < 4; ++mt)
        #pragma unroll
        for (int nt = 0; nt < 4; ++nt) {
            int gn = n0 + wn * 64 + nt * 16 + m16;
            #pragma unroll
            for (int r = 0; r < 4; ++r) {
                int gm = m0 + wm * 64 + mt * 16 + q * 4 + r;
                C[(size_t)gm * NCC + gn] = f2b(acc[mt][nt][r] + bcol[nt]);
            }
        }
}

// ---------------- K3: recurrence, 8 WGs = 2 dirs x 4 batch-groups -----------
// 512 threads = 8 waves; wave w owns gate rows' [w*128, w*128+128) = hu
// [w*32,w*32+32) x 4 gates (interleaved).  fp8 weights in AGPRs (asm "+a"),
// MX-scaled MFMA K=128 with unit scales.  h: LDS fp8 double buffer, one
// barrier/step; h history written via coalesced 8B LDS->global copy.
__global__ __launch_bounds__(512, 2) void lstm_k(const ushort_t* __restrict__ xg,
                                                 const uchar_t* __restrict__ whh8,
                                                 uchar_t* __restrict__ hhist8) {
    const int d  = blockIdx.x >> 2;
    const int bg = blockIdx.x & 3;
    const int tid = threadIdx.x;
    const int w = tid >> 6, lane = tid & 63;
    const int q = lane >> 4, m16 = lane & 15;
    const int bl = bg * 16 + m16;               // this lane's batch (global)

    __shared__ uchar_t hb8[2][16 * HPAD];       // fp8 h, [local batch][hu]
    for (int i = tid; i < 16 * HPAD; i += 512) hb8[0][i] = 0;

    // Weight A-frags: rows' w*128+mt*16+m16, k = kh*128 + q*32 (32B each).
    const uchar_t* wp = whh8 + (size_t)(d * NG + w * 128) * NH;
    v8i wreg[8][2];
    #pragma unroll
    for (int mt = 0; mt < 8; ++mt)
        #pragma unroll
        for (int kh = 0; kh < 2; ++kh)
            wreg[mt][kh] = *(const v8i*)(wp + (size_t)(mt * 16 + m16) * NH + kh * 128 + q * 32);
    #pragma unroll
    for (int mt = 0; mt < 8; ++mt)
        #pragma unroll
        for (int kh = 0; kh < 2; ++kh)
            asm volatile("" : "+a"(wreg[mt][kh]));   // pin in AGPR class

    float c[8];
    #pragma unroll
    for (int i = 0; i < 8; ++i) c[i] = 0.f;
    __syncthreads();

    const int scl = 0x7f7f7f7f;                 // e8m0 scale = 1.0 in all bytes

    #pragma unroll 1
    for (int s = 0; s < NT; ++s) {
        const int t = d ? (NT - 1 - s) : s;

        // xg: 8B per m-tile (4 gates of one hu).
        const ushort_t* xp = xg + (size_t)(t * NB + bl) * NCC + d * NG + w * 128;
        ull_t xr[8];
        #pragma unroll
        for (int mt = 0; mt < 8; ++mt)
            xr[mt] = *(const ull_t*)(xp + mt * 16 + q * 4);

        // B-frags: h_prev fp8 from LDS, 32B per k-half (lane n = batch m16).
        const uchar_t* hrow = &hb8[s & 1][m16 * HPAD];
        v8i hf0 = *(const v8i*)(hrow + q * 32);
        v8i hf1 = *(const v8i*)(hrow + 128 + q * 32);

        floatx4 acc[8];
        #pragma unroll
        for (int mt = 0; mt < 8; ++mt) acc[mt] = (floatx4){0.f, 0.f, 0.f, 0.f};
        #pragma unroll
        for (int mt = 0; mt < 8; ++mt)
            acc[mt] = __builtin_amdgcn_mfma_scale_f32_16x16x128_f8f6f4(
                wreg[mt][0], hf0, acc[mt], 0, 0, 0, scl, 0, scl);
        #pragma unroll
        for (int mt = 0; mt < 8; ++mt)
            acc[mt] = __builtin_amdgcn_mfma_scale_f32_16x16x128_f8f6f4(
                wreg[mt][1], hf1, acc[mt], 0, 0, 0, scl, 0, scl);

        // Epilogue: all 4 gates in-lane (C reg r = gate r of hu w*32+mt*4+q).
        uchar_t* hwr = &hb8[(s + 1) & 1][m16 * HPAD];
        #pragma unroll
        for (int mt = 0; mt < 8; ++mt) {
            const ushort_t* xv = (const ushort_t*)&xr[mt];
            float ig = sigf(acc[mt][0] + b2f(xv[0]));
            float fg = sigf(acc[mt][1] + b2f(xv[1]));
            float gg = tanhfast(acc[mt][2] + b2f(xv[2]));
            float og = sigf(acc[mt][3] + b2f(xv[3]));
            c[mt] = fg * c[mt] + ig * gg;
            float h = og * tanhfast(c[mt]);
            uint_t pk = __builtin_amdgcn_cvt_pk_fp8_f32(h, h, 0, false);
            hwr[w * 32 + mt * 4 + q] = (uchar_t)(pk & 0xFF);
        }
        __syncthreads();
        // Coalesced fp8 h-history write: 4KB per step per WG, 8B/thread.
        {
            int b = tid >> 5, off = (tid & 31) * 8;
            ull_t v = *(const ull_t*)(&hb8[(s + 1) & 1][b * HPAD + off]);
            *(ull_t*)(hhist8 + ((size_t)(d * NT + t) * NB + bg * 16 + b) * NH + off) = v;
        }
    }
}

// ---------------- K4: em[t,b,l] = feats . W_lin[l] + b_lin ------------------
__global__ void em_k(const uchar_t* __restrict__ hhist8, const float* __restrict__ Wlin,
                     const float* __restrict__ blin, float* __restrict__ em) {
    const int t = blockIdx.x;
    const int tid = threadIdx.x;          // 576 threads
    __shared__ float Ws[NL * 520];
    for (int idx = tid; idx < NL * 2 * NH; idx += 576) {
        int l = idx >> 9, k = idx & 511;
        Ws[l * 520 + k] = Wlin[l * 2 * NH + k];
    }
    __syncthreads();
    const int b = tid / NL, l = tid - b * NL;
    const uchar_t* hf = hhist8 + ((size_t)t * NB + b) * NH;
    const uchar_t* hb = hhist8 + ((size_t)(NT + t) * NB + b) * NH;
    float acc = blin[l];
    #pragma unroll 4
    for (int kc = 0; kc < NH / 4; ++kc) {
        uint_t u = *(const uint_t*)(hf + kc * 4);
        floatx2 p0 = __builtin_amdgcn_cvt_pk_f32_fp8(u, false);
        floatx2 p1 = __builtin_amdgcn_cvt_pk_f32_fp8(u, true);
        acc += p0.x * Ws[l * 520 + kc * 4]     + p0.y * Ws[l * 520 + kc * 4 + 1]
             + p1.x * Ws[l * 520 + kc * 4 + 2] + p1.y * Ws[l * 520 + kc * 4 + 3];
    }
    #pragma unroll 4
    for (int kc = 0; kc < NH / 4; ++kc) {
        uint_t u = *(const uint_t*)(hb + kc * 4);
        floatx2 p0 = __builtin_amdgcn_cvt_pk_f32_fp8(u, false);
        floatx2 p1 = __builtin_amdgcn_cvt_pk_f32_fp8(u, true);
        acc += p0.x * Ws[l * 520 + NH + kc * 4]     + p0.y * Ws[l * 520 + NH + kc * 4 + 1]
             + p1.x * Ws[l * 520 + NH + kc * 4 + 2] + p1.y * Ws[l * 520 + NH + kc * 4 + 3];
    }
    em[((size_t)t * NB + b) * NL + l] = acc;
}

// ---------------- K5: CRF numerator per batch (parallel over t) -------------
__global__ void num_k(const float* __restrict__ em, const int* __restrict__ mask,
                      const int* __restrict__ labels, const float* __restrict__ start,
                      const float* __restrict__ endt, const float* __restrict__ trans,
                      float* __restrict__ numbuf) {
    const int b = blockIdx.x;       // 64 blocks x 64 threads (1 wave)
    const int lane = threadIdx.x;
    int cntm = 0;
    for (int t = lane; t < NT; t += 64) cntm += (mask[b * NT + t] != 0);
    #pragma unroll
    for (int off = 32; off > 0; off >>= 1) cntm += __shfl_down(cntm, off);
    const int len = __shfl(cntm, 0);

    float part = 0.f;
    for (int t = lane; t < NT; t += 64) {
        if (t >= 1 && t < len) {
            int tp = labels[b * NT + t - 1];
            int tg = labels[b * NT + t];
            part += trans[tp * NL + tg] + em[((size_t)t * NB + b) * NL + tg];
        }
    }
    #pragma unroll
    for (int off = 32; off > 0; off >>= 1) part += __shfl_down(part, off);
    if (lane == 0) {
        int tag0 = labels[b * NT];
        numbuf[b] = part + start[tag0] + em[(size_t)b * NL + tag0]
                  + endt[labels[b * NT + len - 1]];
    }
}

// ---------------- K6: CRF forward (logZ), diff = logZ - num -----------------
__global__ void crf_k(const float* __restrict__ em, const int* __restrict__ mask,
                      const float* __restrict__ start, const float* __restrict__ endt,
                      const float* __restrict__ trans, const float* __restrict__ numbuf,
                      float* __restrict__ diff) {
    const int b = blockIdx.x;
    const int lane = threadIdx.x;       // 64 threads = 1 wave
    int cnt = 0;
    for (int t = lane; t < NT; t += 64) cnt += (mask[b * NT + t] != 0);
    #pragma unroll
    for (int off = 32; off > 0; off >>= 1) cnt += __shfl_down(cnt, off);
    const int len = __shfl(cnt, 0);

    float tcol[NL];
    #pragma unroll
    for (int i = 0; i < NL; ++i) tcol[i] = (lane < NL) ? trans[i * NL + lane] : 0.f;
    float endv = (lane < NL) ? endt[lane] : 0.f;
    float score = (lane < NL) ? start[lane] + em[(size_t)b * NL + lane] : -1e30f;

    for (int t = 1; t < len; ++t) {
        float emv = (lane < NL) ? em[((size_t)t * NB + b) * NL + lane] : 0.f;
        float sv[NL];
        #pragma unroll
        for (int i = 0; i < NL; ++i) sv[i] = __shfl(score, i) + tcol[i];
        float m = sv[0];
        #pragma unroll
        for (int i = 1; i < NL; ++i) m = fmaxf(m, sv[i]);
        float sum = 0.f;
        #pragma unroll
        for (int i = 0; i < NL; ++i) sum += __expf(sv[i] - m);
        float nxt = m + __logf(sum) + emv;
        if (lane < NL) score = nxt;
    }
    float v = (lane < NL) ? score + endv : -1e30f;
    float m = -1e30f;
    float sv[NL];
    #pragma unroll
    for (int i = 0; i < NL; ++i) { sv[i] = __shfl(v, i); m = fmaxf(m, sv[i]); }
    float sum = 0.f;
    #pragma unroll
    for (int i = 0; i < NL; ++i) sum += __expf(sv[i] - m);
    float logZ = m + __logf(sum);
    if (lane == 0) diff[b] = logZ - numbuf[b];
}

// ---------------- K7: mean over batch -> d_out ------------------------------
__global__ void final_k(const float* __restrict__ diff, float* __restrict__ out) {
    float v = diff[threadIdx.x];
    #pragma unroll
    for (int off = 32; off > 0; off >>= 1) v += __shfl_down(v, off);
    if (threadIdx.x == 0) out[0] = v * (1.0f / NB);
}

extern "C" void kernel_launch(void* const* d_in, const int* in_sizes, int n_in,
                              void* d_out, int out_size, void* d_ws, size_t ws_size,
                              hipStream_t stream) {
    const float* emb   = (const float*)d_in[0];
    const float* Wihf  = (const float*)d_in[1];
    const float* Whhf  = (const float*)d_in[2];
    const float* bf    = (const float*)d_in[3];
    const float* Wihb  = (const float*)d_in[4];
    const float* Whhb  = (const float*)d_in[5];
    const float* bb    = (const float*)d_in[6];
    const float* Wlin  = (const float*)d_in[7];
    const float* blin  = (const float*)d_in[8];
    const float* start = (const float*)d_in[9];
    const float* endt  = (const float*)d_in[10];
    const float* trans = (const float*)d_in[11];
    const int*   mask  = (const int*)d_in[12];
    const int*   labels= (const int*)d_in[13];

    char* ws = (char*)d_ws;
    ushort_t* xbf   = (ushort_t*)(ws + 0);                     // 50,331,648
    ushort_t* wcat  = (ushort_t*)(ws + 50331648);              //  3,145,728
    uchar_t*  whh8  = (uchar_t*) (ws + 53477376);              //    524,288
    float*    bias  = (float*)   (ws + 54001664);              //      8,192
    ushort_t* xg    = (ushort_t*)(ws + 54009856);              // 134,217,728
    uchar_t*  hh8   = (uchar_t*) (ws + 188227584);             // 16,777,216
    float*    em    = (float*)   (ws + 205004800);             //  1,179,648
    float*    numb  = (float*)   (ws + 206184448);             //        256
    float*    diff  = (float*)   (ws + 206184704);             //        256

    conv_x<<<NT * NB * (NE / 4) / 256, 256, 0, stream>>>(emb, xbf);
    conv_w<<<(NCC * NE + NCC * NH / 2 + NCC) / 256, 256, 0, stream>>>(
        Wihf, Wihb, Whhf, Whhb, bf, bb, wcat, whh8, bias);
    gemm_xg<<<dim3(NCC / 128, NT * NB / 128), 256, 0, stream>>>(xbf, wcat, bias, xg);
    lstm_k<<<8, 512, 0, stream>>>(xg, whh8, hh8);
    em_k<<<NT, 576, 0, stream>>>(hh8, Wlin, blin, em);
    num_k<<<NB, 64, 0, stream>>>(em, mask, labels, start, endt, trans, numb);
    crf_k<<<NB, 64, 0, stream>>>(em, mask, start, endt, trans, numb, diff);
    final_k<<<1, 64, 0, stream>>>(diff, (float*)d_out);
}